// Round 14
// baseline (145.749 us; speedup 1.0000x reference)
//
#include <hip/hip_runtime.h>
#include <stdint.h>
#include <type_traits>

typedef short bf16x8 __attribute__((ext_vector_type(8)));
typedef float f32x4  __attribute__((ext_vector_type(4)));
typedef unsigned int u32x2 __attribute__((ext_vector_type(2)));
typedef unsigned short u16;

template<int N> using ic = std::integral_constant<int, N>;

#define BB 2
#define SS 2048
#define DD 1024
#define HH 16
#define NTOK (BB*SS)   // 4096
#define QSC 0.18033688f   // 0.125 * log2(e), folded into Q projection

__device__ __forceinline__ u16 f2bf(float f) {
  union { float f; uint32_t u; } c; c.f = f;
  uint32_t r = c.u + 0x7FFFu + ((c.u >> 16) & 1u);
  return (u16)(r >> 16);
}

// async global->LDS 16B copy (dest must be linear: uniform base + lane*16)
__device__ __forceinline__ void gll16(const void* g, void* l) {
  __builtin_amdgcn_global_load_lds((__attribute__((address_space(1))) void*)(void*)g,
                                   (__attribute__((address_space(3))) void*)l, 16, 0, 0);
}

// ---------------- prep: fp32->bf16 cvt (7 tensors) + padded-key count --------
struct PrepArgs {
  const float* src[7]; u16* dst[7]; int n[7];
  const int* mask; float* padcnt;
};
__global__ __launch_bounds__(256) void prep_kernel(PrepArgs a) {
  const int y = blockIdx.y;
  if (y < 7) {
    const float* __restrict__ src = a.src[y];
    u16* __restrict__ dst = a.dst[y];
    const int n = a.n[y];
    int i = (blockIdx.x * blockDim.x + threadIdx.x) * 4;
    const int stride = gridDim.x * blockDim.x * 4;
    for (; i < n; i += stride) {
      float4 v = *(const float4*)(src + i);
      ushort4 o;
      o.x = f2bf(v.x); o.y = f2bf(v.y); o.z = f2bf(v.z); o.w = f2bf(v.w);
      *(ushort4*)(dst + i) = o;
    }
  } else {
    if (blockIdx.x >= BB) return;
    const int b = blockIdx.x, t = threadIdx.x;
    const int4 v1 = *(const int4*)(a.mask + b * SS + t * 8);
    const int4 v2 = *(const int4*)(a.mask + b * SS + t * 8 + 4);
    int s = v1.x + v1.y + v1.z + v1.w + v2.x + v2.y + v2.z + v2.w;
#pragma unroll
    for (int off = 32; off; off >>= 1) s += __shfl_xor(s, off);
    __shared__ int red[4];
    if ((t & 63) == 0) red[t >> 6] = s;
    __syncthreads();
    if (t == 0) a.padcnt[b] = (float)(red[0] + red[1] + red[2] + red[3]);
  }
}

// ---------------- GEMM: C[4096,1024] = A[4096,1024] * W^T + bias ----------------
// R11 sync structure (stage(t+1) BEFORE compute(t), single __syncthreads) +
// pointer-increment staging + compile-time buffer index (x2 unroll).
// R12/R13 counted-vmcnt variant measured SLOWER (54.2 vs <52.6) - reverted.
template<int MODE>
__device__ __forceinline__ void gemm_bt_body(const u16* __restrict__ A,
                                             const u16* __restrict__ W,
                                             const float* __restrict__ bias,
                                             const int* __restrict__ mask,
                                             void* __restrict__ Cout,
                                             int m0, int n0,
                                             u16* As, u16* Bs) {
  const int tid = threadIdx.x;
  const int lane = tid & 63, wid = tid >> 6;
  const int r16 = lane & 15, g4 = lane >> 4;
  const int wm = (wid >> 1) * 64, wn = (wid & 1) * 64;

  const f32x4 zero = {0.f, 0.f, 0.f, 0.f};
  f32x4 acc[4][4];
#pragma unroll
  for (int i = 0; i < 4; ++i)
#pragma unroll
    for (int j = 0; j < 4; ++j) acc[i][j] = zero;

  // staging pointers, advanced +32 elems per stage call (call order = tile order)
  const u16* aptr[2];
  const u16* wptr[2];
  {
    const int row0 = tid >> 2, blk0 = tid & 3;
#pragma unroll
    for (int it = 0; it < 2; ++it) {
      const int row = row0 + it * 64;
      const int sb = blk0 ^ (row & 3);
      aptr[it] = A + (size_t)(m0 + row) * DD + sb * 8;
      wptr[it] = W + (size_t)(n0 + row) * DD + sb * 8;
    }
  }
  auto stage = [&](int buf) {
#pragma unroll
    for (int it = 0; it < 2; ++it) {
      gll16(aptr[it], As + buf * 4096 + (tid + it * 256) * 8);
      gll16(wptr[it], Bs + buf * 4096 + (tid + it * 256) * 8);
      aptr[it] += 32; wptr[it] += 32;
    }
  };

  stage(0);
  __syncthreads();

  auto kstep = [&](auto CURC, int kt) {
    constexpr int cur = decltype(CURC)::value;
    if (kt + 1 < DD / 32) stage(cur ^ 1);
    bf16x8 af[4], bfr[4];
#pragma unroll
    for (int i = 0; i < 4; ++i) {
      const int ar = wm + i * 16 + r16;
      af[i] = *(const bf16x8*)(As + cur * 4096 + ar * 32 + ((g4 ^ (ar & 3)) << 3));
      const int br = wn + i * 16 + r16;
      bfr[i] = *(const bf16x8*)(Bs + cur * 4096 + br * 32 + ((g4 ^ (br & 3)) << 3));
    }
#pragma unroll
    for (int i = 0; i < 4; ++i)
#pragma unroll
      for (int j = 0; j < 4; ++j)
        acc[i][j] = __builtin_amdgcn_mfma_f32_16x16x32_bf16(af[i], bfr[j], acc[i][j], 0, 0, 0);
    __syncthreads();   // drain covered by the compute above (stage issued first)
  };
  for (int kt = 0; kt < DD / 32; kt += 2) {
    kstep(ic<0>{}, kt);
    kstep(ic<1>{}, kt + 1);
  }

  // epilogue: D layout col = lane&15, row = (lane>>4)*4 + r
  float bcol[4];
#pragma unroll
  for (int j = 0; j < 4; ++j) bcol[j] = bias[n0 + wn + j * 16 + r16];

#pragma unroll
  for (int i = 0; i < 4; ++i) {
    const int rowb = m0 + wm + i * 16 + g4 * 4;
    int mr[4] = {0, 0, 0, 0};
    if (MODE == 1 || MODE == 2) {
      const int4 mv = *(const int4*)(mask + rowb);
      mr[0] = mv.x; mr[1] = mv.y; mr[2] = mv.z; mr[3] = mv.w;
    }
#pragma unroll
    for (int j = 0; j < 4; ++j) {
      const int col = n0 + wn + j * 16 + r16;
      if (MODE == 3) {
#pragma unroll
        for (int r = 0; r < 4; ++r)
          ((float*)Cout)[(size_t)(rowb + r) * DD + col] = acc[i][j][r] + bcol[j];
      } else if (MODE == 0) {
#pragma unroll
        for (int r = 0; r < 4; ++r)
          ((u16*)Cout)[(size_t)(rowb + r) * DD + col] = f2bf((acc[i][j][r] + bcol[j]) * QSC);
      } else if (MODE == 1) {
#pragma unroll
        for (int r = 0; r < 4; ++r) {
          const float v = mr[r] ? 0.f : (acc[i][j][r] + bcol[j]);
          ((u16*)Cout)[(size_t)(rowb + r) * DD + col] = f2bf(v);
        }
      } else {  // MODE 2: transposed V store
        const int bb = rowb >> 11, s0 = rowb & (SS - 1);
        ushort4 pk;
        pk.x = f2bf(mr[0] ? 0.f : (acc[i][j][0] + bcol[j]));
        pk.y = f2bf(mr[1] ? 0.f : (acc[i][j][1] + bcol[j]));
        pk.z = f2bf(mr[2] ? 0.f : (acc[i][j][2] + bcol[j]));
        pk.w = f2bf(mr[3] ? 0.f : (acc[i][j][3] + bcol[j]));
        *(ushort4*)((u16*)Cout + (size_t)(bb * DD + col) * SS + s0) = pk;
      }
    }
  }
}

struct QkvArgs {
  const u16* A[3];
  const u16* W[3];
  const float* bias[3];
  const int* mask;
  u16* outq; u16* outk; u16* outv;   // outv = Vt [b*DD+d][s]
};

__global__ __launch_bounds__(256) void gemm_qkv_kernel(QkvArgs a) {
  __shared__ __align__(16) u16 As[2][4096];
  __shared__ __align__(16) u16 Bs[2][4096];
  // XCD swizzle: 768 blocks, 96 contiguous works per XCD (bijective: 768%8==0)
  const int fid = blockIdx.x + (blockIdx.y << 3) + (blockIdx.z << 8);
  const int swz = (fid & 7) * 96 + (fid >> 3);
  const int z = swz >> 8;
  const int rem = swz & 255;
  const int m0 = (rem >> 3) * 128, n0 = (rem & 7) * 128;
  if (z == 0)      gemm_bt_body<0>(a.A[0], a.W[0], a.bias[0], nullptr, (void*)a.outq, m0, n0, &As[0][0], &Bs[0][0]);
  else if (z == 1) gemm_bt_body<1>(a.A[1], a.W[1], a.bias[1], a.mask, (void*)a.outk, m0, n0, &As[0][0], &Bs[0][0]);
  else             gemm_bt_body<2>(a.A[2], a.W[2], a.bias[2], a.mask, (void*)a.outv, m0, n0, &As[0][0], &Bs[0][0]);
}

__global__ __launch_bounds__(256) void gemm_out_kernel(const u16* __restrict__ A,
                                                       const u16* __restrict__ W,
                                                       const float* __restrict__ bias,
                                                       float* __restrict__ C) {
  __shared__ __align__(16) u16 As[2][4096];
  __shared__ __align__(16) u16 Bs[2][4096];
  const int fid = blockIdx.x + (blockIdx.y << 3);          // 256 blocks
  const int swz = (fid & 7) * 32 + (fid >> 3);
  const int m0 = (swz >> 3) * 128, n0 = (swz & 7) * 128;
  gemm_bt_body<3>(A, W, bias, nullptr, (void*)C, m0, n0, &As[0][0], &Bs[0][0]);
}

// ---------------- Flash attention (R11 structure: measured 52.6us) ----------
// grid (S/64, H, B) XCD-swizzled; 256 threads = 4 waves, 16 q-rows each.
// Swapped QK^T + in-register P redistribution; K/V dbuf; stage(t+1) issued
// BEFORE compute(t); single __syncthreads per step (drain covered by compute).
#define NT (SS / 64)
__global__ __launch_bounds__(256) void attn_kernel(const u16* __restrict__ Qp,
                                                   const u16* __restrict__ Kp,
                                                   const u16* __restrict__ Vt,
                                                   const float* __restrict__ padcnt,
                                                   u16* __restrict__ ctx) {
  __shared__ __align__(16) u16 Ks[2][64 * 64];
  __shared__ __align__(16) u16 Vs[2][64 * 64];

  const int tid = threadIdx.x;
  const int lane = tid & 63, wid = tid >> 6;
  const int r16 = lane & 15, g4 = lane >> 4;
  // XCD swizzle: 1024 blocks -> 128 contiguous works per XCD
  const int fid = blockIdx.x + 32 * (blockIdx.y + 16 * blockIdx.z);
  const int swz = (fid & 7) * 128 + (fid >> 3);
  const int qt = swz & 31, rem = swz >> 5;
  const int h = rem & 15, b = rem >> 4;

  const int qtok = b * SS + qt * 64 + wid * 16 + r16;
  bf16x8 qf[2];
#pragma unroll
  for (int c = 0; c < 2; ++c)
    qf[c] = *(const bf16x8*)(Qp + (size_t)qtok * DD + h * 64 + c * 32 + g4 * 8);

  const f32x4 zero = {0.f, 0.f, 0.f, 0.f};
  f32x4 o[4];
#pragma unroll
  for (int j = 0; j < 4; ++j) o[j] = zero;
  float ll = 0.f;   // per-lane partial of l[q = r16]

  // staging pointers: K advances +64*DD, V advances +64 per stage call
  const u16* kptr[2];
  const u16* vptr[2];
  {
    const int srow0 = tid >> 3, sblk0 = tid & 7;
#pragma unroll
    for (int it = 0; it < 2; ++it) {
      const int row = srow0 + it * 32;
      const int sb = sblk0 ^ (row & 7);
      kptr[it] = Kp + (size_t)(b * SS + row) * DD + h * 64 + sb * 8;
      vptr[it] = Vt + (size_t)(b * DD + h * 64 + row) * SS + sb * 8;
    }
  }
  auto stage = [&](int buf) {
#pragma unroll
    for (int it = 0; it < 2; ++it) {
      gll16(kptr[it], &Ks[buf][(tid + it * 256) * 8]);
      gll16(vptr[it], &Vs[buf][(tid + it * 256) * 8]);
      kptr[it] += 64 * DD;
      vptr[it] += 64;
    }
  };

  stage(0);
  __syncthreads();

  auto tile_step = [&](auto CURC, int kt) {
    constexpr int cur = decltype(CURC)::value;
    if (kt + 1 < NT) stage(cur ^ 1);

    // S^T = K Q^T : col = q (r16), row = key = j*16 + g4*4 + r
    f32x4 st[4];
    __builtin_amdgcn_s_setprio(1);
#pragma unroll
    for (int j = 0; j < 4; ++j) {
      const int kr = j * 16 + r16;
      const bf16x8 kf = *(const bf16x8*)(&Ks[cur][kr * 64 + ((g4 ^ (kr & 7)) << 3)]);
      st[j] = __builtin_amdgcn_mfma_f32_16x16x32_bf16(kf, qf[0], zero, 0, 0, 0);
    }
#pragma unroll
    for (int j = 0; j < 4; ++j) {
      const int kr = j * 16 + r16;
      const bf16x8 kf = *(const bf16x8*)(&Ks[cur][kr * 64 + (((4 + g4) ^ (kr & 7)) << 3)]);
      st[j] = __builtin_amdgcn_mfma_f32_16x16x32_bf16(kf, qf[1], st[j], 0, 0, 0);
    }
    __builtin_amdgcn_s_setprio(0);

    // p = 2^st (Q pre-scaled); pack key-pairs to bf16
    uint32_t q0[4], q1[4];
#pragma unroll
    for (int j = 0; j < 4; ++j) {
      float p0, p1, p2, p3;
      asm("v_exp_f32 %0, %1" : "=v"(p0) : "v"(st[j][0]));
      asm("v_exp_f32 %0, %1" : "=v"(p1) : "v"(st[j][1]));
      asm("v_exp_f32 %0, %1" : "=v"(p2) : "v"(st[j][2]));
      asm("v_exp_f32 %0, %1" : "=v"(p3) : "v"(st[j][3]));
      ll += (p0 + p1) + (p2 + p3);
      asm("v_cvt_pk_bf16_f32 %0, %1, %2" : "=v"(q0[j]) : "v"(p0), "v"(p1));
      asm("v_cvt_pk_bf16_f32 %0, %1, %2" : "=v"(q1[j]) : "v"(p2), "v"(p3));
    }

    // in-register P redistribution -> PV A-frags
    bf16x8 pa[2];
#pragma unroll
    for (int c = 0; c < 2; ++c) {
      u32x2 s0 = __builtin_amdgcn_permlane32_swap(q0[2 * c], q0[2 * c + 1], false, false);
      u32x2 s1 = __builtin_amdgcn_permlane16_swap(s0.x, s0.y, false, false);
      u32x2 t0 = __builtin_amdgcn_permlane32_swap(q1[2 * c], q1[2 * c + 1], false, false);
      u32x2 t1 = __builtin_amdgcn_permlane16_swap(t0.x, t0.y, false, false);
      union { uint32_t u[4]; bf16x8 v; } cv;
      cv.u[0] = s1.x; cv.u[1] = t1.x; cv.u[2] = s1.y; cv.u[3] = t1.y;
      pa[c] = cv.v;
    }

    // O += P V
    __builtin_amdgcn_s_setprio(1);
#pragma unroll
    for (int c = 0; c < 2; ++c)
#pragma unroll
      for (int j = 0; j < 4; ++j) {
        const int vr = j * 16 + r16;
        const bf16x8 vf = *(const bf16x8*)(&Vs[cur][vr * 64 + (((c * 4 + g4) ^ (vr & 7)) << 3)]);
        o[j] = __builtin_amdgcn_mfma_f32_16x16x32_bf16(pa[c], vf, o[j], 0, 0, 0);
      }
    __builtin_amdgcn_s_setprio(0);
    __syncthreads();   // drain covered by the compute above (stage issued first)
  };

  for (int kt = 0; kt < NT; kt += 2) {
    tile_step(ic<0>{}, kt);
    tile_step(ic<1>{}, kt + 1);
  }

  // finish l[q=r16]: reduce across g4 groups, subtract padded count
  ll += __shfl_xor(ll, 16);
  ll += __shfl_xor(ll, 32);
  ll -= padcnt[b];
  const float inv = 1.0f / ll;
  float invr[4];
#pragma unroll
  for (int r = 0; r < 4; ++r) invr[r] = __shfl(inv, g4 * 4 + r);

  // epilogue: O D-layout row = g4*4 + r, col = j*16 + r16
  const int otok = b * SS + qt * 64 + wid * 16 + g4 * 4;
#pragma unroll
  for (int j = 0; j < 4; ++j) {
    const int col = h * 64 + j * 16 + r16;
#pragma unroll
    for (int r = 0; r < 4; ++r)
      ctx[(size_t)(otok + r) * DD + col] = f2bf(o[j][r] * invr[r]);
  }
}

extern "C" void kernel_launch(void* const* d_in, const int* in_sizes, int n_in,
                              void* d_out, int out_size, void* d_ws, size_t ws_size,
                              hipStream_t stream) {
  (void)in_sizes; (void)n_in; (void)out_size; (void)ws_size;
  const float* f_q = (const float*)d_in[0];
  const float* f_k = (const float*)d_in[1];
  const float* f_v = (const float*)d_in[2];
  const int* mask  = (const int*)d_in[3];
  const float* Wq = (const float*)d_in[4];
  const float* bq = (const float*)d_in[5];
  const float* Wk = (const float*)d_in[6];
  const float* bk = (const float*)d_in[7];
  const float* Wv = (const float*)d_in[8];
  const float* bv = (const float*)d_in[9];
  const float* Wo = (const float*)d_in[10];
  const float* bo = (const float*)d_in[11];

  char* ws = (char*)d_ws;
  const size_t XB = (size_t)NTOK * DD * 2;   // 8 MB per token-matrix (bf16)
  const size_t WB = (size_t)DD * DD * 2;     // 2 MB per weight (bf16)
  u16* Xq  = (u16*)(ws);                     // reused as ctx after QKV gemm
  u16* Xk  = (u16*)(ws + XB);
  u16* Xv  = (u16*)(ws + 2 * XB);
  u16* Qp  = (u16*)(ws + 3 * XB);
  u16* Kp  = (u16*)(ws + 4 * XB);
  u16* Vt  = (u16*)(ws + 5 * XB);            // [2*1024][2048]
  u16* Wqb = (u16*)(ws + 6 * XB);
  u16* Wkb = (u16*)(ws + 6 * XB + WB);
  u16* Wvb = (u16*)(ws + 6 * XB + 2 * WB);
  u16* Wob = (u16*)(ws + 6 * XB + 3 * WB);
  float* padcnt = (float*)(ws + 6 * XB + 4 * WB);
  u16* ctx = Xq;

  PrepArgs pa;
  pa.src[0] = f_q; pa.src[1] = f_k; pa.src[2] = f_v;
  pa.src[3] = Wq;  pa.src[4] = Wk;  pa.src[5] = Wv;  pa.src[6] = Wo;
  pa.dst[0] = Xq;  pa.dst[1] = Xk;  pa.dst[2] = Xv;
  pa.dst[3] = Wqb; pa.dst[4] = Wkb; pa.dst[5] = Wvb; pa.dst[6] = Wob;
  pa.n[0] = pa.n[1] = pa.n[2] = NTOK * DD;
  pa.n[3] = pa.n[4] = pa.n[5] = pa.n[6] = DD * DD;
  pa.mask = mask; pa.padcnt = padcnt;
  prep_kernel<<<dim3(1024, 8), 256, 0, stream>>>(pa);

  QkvArgs qa;
  qa.A[0] = Xq;  qa.A[1] = Xk;  qa.A[2] = Xv;
  qa.W[0] = Wqb; qa.W[1] = Wkb; qa.W[2] = Wvb;
  qa.bias[0] = bq; qa.bias[1] = bk; qa.bias[2] = bv;
  qa.mask = mask;
  qa.outq = Qp; qa.outk = Kp; qa.outv = Vt;
  gemm_qkv_kernel<<<dim3(DD / 128, NTOK / 128, 3), 256, 0, stream>>>(qa);

  attn_kernel<<<dim3(SS / 64, HH, BB), 256, 0, stream>>>(Qp, Kp, Vt, padcnt, ctx);
  gemm_out_kernel<<<dim3(DD / 128, NTOK / 128), 256, 0, stream>>>(ctx, Wob, bo, (float*)d_out);
}

// Round 15
// 138.776 us; speedup vs baseline: 1.0502x; 1.0502x over previous
//
#include <hip/hip_runtime.h>
#include <stdint.h>
#include <type_traits>

typedef short bf16x8 __attribute__((ext_vector_type(8)));
typedef float f32x4  __attribute__((ext_vector_type(4)));
typedef unsigned int u32x2 __attribute__((ext_vector_type(2)));
typedef unsigned short u16;

template<int N> using ic = std::integral_constant<int, N>;

#define BB 2
#define SS 2048
#define DD 1024
#define HH 16
#define NTOK (BB*SS)   // 4096
#define QSC 0.18033688f   // 0.125 * log2(e), folded into Q projection

__device__ __forceinline__ u16 f2bf(float f) {
  union { float f; uint32_t u; } c; c.f = f;
  uint32_t r = c.u + 0x7FFFu + ((c.u >> 16) & 1u);
  return (u16)(r >> 16);
}

// async global->LDS 16B copy (dest must be linear: uniform base + lane*16)
__device__ __forceinline__ void gll16(const void* g, void* l) {
  __builtin_amdgcn_global_load_lds((__attribute__((address_space(1))) void*)(void*)g,
                                   (__attribute__((address_space(3))) void*)l, 16, 0, 0);
}

// ---------------- prep: fp32->bf16 cvt (7 tensors) + padded-key count --------
struct PrepArgs {
  const float* src[7]; u16* dst[7]; int n[7];
  const int* mask; float* padcnt;
};
__global__ __launch_bounds__(256) void prep_kernel(PrepArgs a) {
  const int y = blockIdx.y;
  if (y < 7) {
    const float* __restrict__ src = a.src[y];
    u16* __restrict__ dst = a.dst[y];
    const int n = a.n[y];
    int i = (blockIdx.x * blockDim.x + threadIdx.x) * 4;
    const int stride = gridDim.x * blockDim.x * 4;
    for (; i < n; i += stride) {
      float4 v = *(const float4*)(src + i);
      ushort4 o;
      o.x = f2bf(v.x); o.y = f2bf(v.y); o.z = f2bf(v.z); o.w = f2bf(v.w);
      *(ushort4*)(dst + i) = o;
    }
  } else {
    if (blockIdx.x >= BB) return;
    const int b = blockIdx.x, t = threadIdx.x;
    const int4 v1 = *(const int4*)(a.mask + b * SS + t * 8);
    const int4 v2 = *(const int4*)(a.mask + b * SS + t * 8 + 4);
    int s = v1.x + v1.y + v1.z + v1.w + v2.x + v2.y + v2.z + v2.w;
#pragma unroll
    for (int off = 32; off; off >>= 1) s += __shfl_xor(s, off);
    __shared__ int red[4];
    if ((t & 63) == 0) red[t >> 6] = s;
    __syncthreads();
    if (t == 0) a.padcnt[b] = (float)(red[0] + red[1] + red[2] + red[3]);
  }
}

// ---------------- GEMM: C[4096,1024] = A[4096,1024] * W^T + bias ----------------
// R8/R11 measured-best configuration: bf16 A, shared 32KB LDS dbuf, runtime
// buffer index, stage(t+1) issued BEFORE compute(t), single __syncthreads,
// no setprio, no pins, no unroll. All four "optimized" variants (counted
// vmcnt R12/R13, ptr-inc+unroll R14) measured slower.
template<int MODE>
__device__ __forceinline__ void gemm_bt_body(const u16* __restrict__ A,
                                             const u16* __restrict__ W,
                                             const float* __restrict__ bias,
                                             const int* __restrict__ mask,
                                             void* __restrict__ Cout,
                                             int m0, int n0,
                                             u16* As, u16* Bs) {
  const int tid = threadIdx.x;
  const int lane = tid & 63, wid = tid >> 6;
  const int r16 = lane & 15, g4 = lane >> 4;
  const int wm = (wid >> 1) * 64, wn = (wid & 1) * 64;

  const f32x4 zero = {0.f, 0.f, 0.f, 0.f};
  f32x4 acc[4][4];
#pragma unroll
  for (int i = 0; i < 4; ++i)
#pragma unroll
    for (int j = 0; j < 4; ++j) acc[i][j] = zero;

  const int row0 = tid >> 2, blk0 = tid & 3;
  auto stage = [&](int kt, int buf) {
#pragma unroll
    for (int it = 0; it < 2; ++it) {
      const int row = row0 + it * 64;
      const int sb = blk0 ^ (row & 3);
      gll16(A + (size_t)(m0 + row) * DD + kt * 32 + sb * 8,
            As + buf * 4096 + (tid + it * 256) * 8);
      gll16(W + (size_t)(n0 + row) * DD + kt * 32 + sb * 8,
            Bs + buf * 4096 + (tid + it * 256) * 8);
    }
  };

  stage(0, 0);
  __syncthreads();

  for (int kt = 0; kt < DD / 32; ++kt) {
    const int cur = kt & 1;
    if (kt + 1 < DD / 32) stage(kt + 1, cur ^ 1);

    bf16x8 af[4], bfr[4];
#pragma unroll
    for (int i = 0; i < 4; ++i) {
      const int ar = wm + i * 16 + r16;
      af[i] = *(const bf16x8*)(As + cur * 4096 + ar * 32 + ((g4 ^ (ar & 3)) << 3));
      const int br = wn + i * 16 + r16;
      bfr[i] = *(const bf16x8*)(Bs + cur * 4096 + br * 32 + ((g4 ^ (br & 3)) << 3));
    }
#pragma unroll
    for (int i = 0; i < 4; ++i)
#pragma unroll
      for (int j = 0; j < 4; ++j)
        acc[i][j] = __builtin_amdgcn_mfma_f32_16x16x32_bf16(af[i], bfr[j], acc[i][j], 0, 0, 0);
    __syncthreads();   // drain covered by the compute above (stage issued first)
  }

  // epilogue: D layout col = lane&15, row = (lane>>4)*4 + r
  float bcol[4];
#pragma unroll
  for (int j = 0; j < 4; ++j) bcol[j] = bias[n0 + wn + j * 16 + r16];

#pragma unroll
  for (int i = 0; i < 4; ++i) {
    const int rowb = m0 + wm + i * 16 + g4 * 4;
    int mr[4] = {0, 0, 0, 0};
    if (MODE == 1 || MODE == 2) {
      const int4 mv = *(const int4*)(mask + rowb);
      mr[0] = mv.x; mr[1] = mv.y; mr[2] = mv.z; mr[3] = mv.w;
    }
#pragma unroll
    for (int j = 0; j < 4; ++j) {
      const int col = n0 + wn + j * 16 + r16;
      if (MODE == 3) {
#pragma unroll
        for (int r = 0; r < 4; ++r)
          ((float*)Cout)[(size_t)(rowb + r) * DD + col] = acc[i][j][r] + bcol[j];
      } else if (MODE == 0) {
#pragma unroll
        for (int r = 0; r < 4; ++r)
          ((u16*)Cout)[(size_t)(rowb + r) * DD + col] = f2bf((acc[i][j][r] + bcol[j]) * QSC);
      } else if (MODE == 1) {
#pragma unroll
        for (int r = 0; r < 4; ++r) {
          const float v = mr[r] ? 0.f : (acc[i][j][r] + bcol[j]);
          ((u16*)Cout)[(size_t)(rowb + r) * DD + col] = f2bf(v);
        }
      } else {  // MODE 2: transposed V store
        const int bb = rowb >> 11, s0 = rowb & (SS - 1);
        ushort4 pk;
        pk.x = f2bf(mr[0] ? 0.f : (acc[i][j][0] + bcol[j]));
        pk.y = f2bf(mr[1] ? 0.f : (acc[i][j][1] + bcol[j]));
        pk.z = f2bf(mr[2] ? 0.f : (acc[i][j][2] + bcol[j]));
        pk.w = f2bf(mr[3] ? 0.f : (acc[i][j][3] + bcol[j]));
        *(ushort4*)((u16*)Cout + (size_t)(bb * DD + col) * SS + s0) = pk;
      }
    }
  }
}

struct QkvArgs {
  const u16* A[3];
  const u16* W[3];
  const float* bias[3];
  const int* mask;
  u16* outq; u16* outk; u16* outv;   // outv = Vt [b*DD+d][s]
};

__global__ __launch_bounds__(256) void gemm_qkv_kernel(QkvArgs a) {
  __shared__ __align__(16) u16 As[2][4096];
  __shared__ __align__(16) u16 Bs[2][4096];
  // XCD swizzle: 768 blocks, 96 contiguous works per XCD (bijective: 768%8==0)
  const int fid = blockIdx.x + (blockIdx.y << 3) + (blockIdx.z << 8);
  const int swz = (fid & 7) * 96 + (fid >> 3);
  const int z = swz >> 8;
  const int rem = swz & 255;
  const int m0 = (rem >> 3) * 128, n0 = (rem & 7) * 128;
  if (z == 0)      gemm_bt_body<0>(a.A[0], a.W[0], a.bias[0], nullptr, (void*)a.outq, m0, n0, &As[0][0], &Bs[0][0]);
  else if (z == 1) gemm_bt_body<1>(a.A[1], a.W[1], a.bias[1], a.mask, (void*)a.outk, m0, n0, &As[0][0], &Bs[0][0]);
  else             gemm_bt_body<2>(a.A[2], a.W[2], a.bias[2], a.mask, (void*)a.outv, m0, n0, &As[0][0], &Bs[0][0]);
}

__global__ __launch_bounds__(256) void gemm_out_kernel(const u16* __restrict__ A,
                                                       const u16* __restrict__ W,
                                                       const float* __restrict__ bias,
                                                       float* __restrict__ C) {
  __shared__ __align__(16) u16 As[2][4096];
  __shared__ __align__(16) u16 Bs[2][4096];
  const int fid = blockIdx.x + (blockIdx.y << 3);          // 256 blocks
  const int swz = (fid & 7) * 32 + (fid >> 3);
  const int m0 = (swz >> 3) * 128, n0 = (swz & 7) * 128;
  gemm_bt_body<3>(A, W, bias, nullptr, (void*)C, m0, n0, &As[0][0], &Bs[0][0]);
}

// ---------------- Flash attention (R11 structure: measured 52.6us) ----------
// grid (S/64, H, B) XCD-swizzled; 256 threads = 4 waves, 16 q-rows each.
// Swapped QK^T + in-register P redistribution; K/V dbuf; stage(t+1) issued
// BEFORE compute(t); single __syncthreads per step (drain covered by compute).
#define NT (SS / 64)
__global__ __launch_bounds__(256) void attn_kernel(const u16* __restrict__ Qp,
                                                   const u16* __restrict__ Kp,
                                                   const u16* __restrict__ Vt,
                                                   const float* __restrict__ padcnt,
                                                   u16* __restrict__ ctx) {
  __shared__ __align__(16) u16 Ks[2][64 * 64];
  __shared__ __align__(16) u16 Vs[2][64 * 64];

  const int tid = threadIdx.x;
  const int lane = tid & 63, wid = tid >> 6;
  const int r16 = lane & 15, g4 = lane >> 4;
  // XCD swizzle: 1024 blocks -> 128 contiguous works per XCD
  const int fid = blockIdx.x + 32 * (blockIdx.y + 16 * blockIdx.z);
  const int swz = (fid & 7) * 128 + (fid >> 3);
  const int qt = swz & 31, rem = swz >> 5;
  const int h = rem & 15, b = rem >> 4;

  const int qtok = b * SS + qt * 64 + wid * 16 + r16;
  bf16x8 qf[2];
#pragma unroll
  for (int c = 0; c < 2; ++c)
    qf[c] = *(const bf16x8*)(Qp + (size_t)qtok * DD + h * 64 + c * 32 + g4 * 8);

  const f32x4 zero = {0.f, 0.f, 0.f, 0.f};
  f32x4 o[4];
#pragma unroll
  for (int j = 0; j < 4; ++j) o[j] = zero;
  float ll = 0.f;   // per-lane partial of l[q = r16]

  // staging pointers: K advances +64*DD, V advances +64 per stage call
  const u16* kptr[2];
  const u16* vptr[2];
  {
    const int srow0 = tid >> 3, sblk0 = tid & 7;
#pragma unroll
    for (int it = 0; it < 2; ++it) {
      const int row = srow0 + it * 32;
      const int sb = sblk0 ^ (row & 7);
      kptr[it] = Kp + (size_t)(b * SS + row) * DD + h * 64 + sb * 8;
      vptr[it] = Vt + (size_t)(b * DD + h * 64 + row) * SS + sb * 8;
    }
  }
  auto stage = [&](int buf) {
#pragma unroll
    for (int it = 0; it < 2; ++it) {
      gll16(kptr[it], &Ks[buf][(tid + it * 256) * 8]);
      gll16(vptr[it], &Vs[buf][(tid + it * 256) * 8]);
      kptr[it] += 64 * DD;
      vptr[it] += 64;
    }
  };

  stage(0);
  __syncthreads();

  auto tile_step = [&](auto CURC, int kt) {
    constexpr int cur = decltype(CURC)::value;
    if (kt + 1 < NT) stage(cur ^ 1);

    // S^T = K Q^T : col = q (r16), row = key = j*16 + g4*4 + r
    f32x4 st[4];
    __builtin_amdgcn_s_setprio(1);
#pragma unroll
    for (int j = 0; j < 4; ++j) {
      const int kr = j * 16 + r16;
      const bf16x8 kf = *(const bf16x8*)(&Ks[cur][kr * 64 + ((g4 ^ (kr & 7)) << 3)]);
      st[j] = __builtin_amdgcn_mfma_f32_16x16x32_bf16(kf, qf[0], zero, 0, 0, 0);
    }
#pragma unroll
    for (int j = 0; j < 4; ++j) {
      const int kr = j * 16 + r16;
      const bf16x8 kf = *(const bf16x8*)(&Ks[cur][kr * 64 + (((4 + g4) ^ (kr & 7)) << 3)]);
      st[j] = __builtin_amdgcn_mfma_f32_16x16x32_bf16(kf, qf[1], st[j], 0, 0, 0);
    }
    __builtin_amdgcn_s_setprio(0);

    // p = 2^st (Q pre-scaled); pack key-pairs to bf16
    uint32_t q0[4], q1[4];
#pragma unroll
    for (int j = 0; j < 4; ++j) {
      float p0, p1, p2, p3;
      asm("v_exp_f32 %0, %1" : "=v"(p0) : "v"(st[j][0]));
      asm("v_exp_f32 %0, %1" : "=v"(p1) : "v"(st[j][1]));
      asm("v_exp_f32 %0, %1" : "=v"(p2) : "v"(st[j][2]));
      asm("v_exp_f32 %0, %1" : "=v"(p3) : "v"(st[j][3]));
      ll += (p0 + p1) + (p2 + p3);
      asm("v_cvt_pk_bf16_f32 %0, %1, %2" : "=v"(q0[j]) : "v"(p0), "v"(p1));
      asm("v_cvt_pk_bf16_f32 %0, %1, %2" : "=v"(q1[j]) : "v"(p2), "v"(p3));
    }

    // in-register P redistribution -> PV A-frags
    bf16x8 pa[2];
#pragma unroll
    for (int c = 0; c < 2; ++c) {
      u32x2 s0 = __builtin_amdgcn_permlane32_swap(q0[2 * c], q0[2 * c + 1], false, false);
      u32x2 s1 = __builtin_amdgcn_permlane16_swap(s0.x, s0.y, false, false);
      u32x2 t0 = __builtin_amdgcn_permlane32_swap(q1[2 * c], q1[2 * c + 1], false, false);
      u32x2 t1 = __builtin_amdgcn_permlane16_swap(t0.x, t0.y, false, false);
      union { uint32_t u[4]; bf16x8 v; } cv;
      cv.u[0] = s1.x; cv.u[1] = t1.x; cv.u[2] = s1.y; cv.u[3] = t1.y;
      pa[c] = cv.v;
    }

    // O += P V
    __builtin_amdgcn_s_setprio(1);
#pragma unroll
    for (int c = 0; c < 2; ++c)
#pragma unroll
      for (int j = 0; j < 4; ++j) {
        const int vr = j * 16 + r16;
        const bf16x8 vf = *(const bf16x8*)(&Vs[cur][vr * 64 + (((c * 4 + g4) ^ (vr & 7)) << 3)]);
        o[j] = __builtin_amdgcn_mfma_f32_16x16x32_bf16(pa[c], vf, o[j], 0, 0, 0);
      }
    __builtin_amdgcn_s_setprio(0);
    __syncthreads();   // drain covered by the compute above (stage issued first)
  };

  for (int kt = 0; kt < NT; kt += 2) {
    tile_step(ic<0>{}, kt);
    tile_step(ic<1>{}, kt + 1);
  }

  // finish l[q=r16]: reduce across g4 groups, subtract padded count
  ll += __shfl_xor(ll, 16);
  ll += __shfl_xor(ll, 32);
  ll -= padcnt[b];
  const float inv = 1.0f / ll;
  float invr[4];
#pragma unroll
  for (int r = 0; r < 4; ++r) invr[r] = __shfl(inv, g4 * 4 + r);

  // epilogue: O D-layout row = g4*4 + r, col = j*16 + r16
  const int otok = b * SS + qt * 64 + wid * 16 + g4 * 4;
#pragma unroll
  for (int j = 0; j < 4; ++j) {
    const int col = h * 64 + j * 16 + r16;
#pragma unroll
    for (int r = 0; r < 4; ++r)
      ctx[(size_t)(otok + r) * DD + col] = f2bf(o[j][r] * invr[r]);
  }
}

extern "C" void kernel_launch(void* const* d_in, const int* in_sizes, int n_in,
                              void* d_out, int out_size, void* d_ws, size_t ws_size,
                              hipStream_t stream) {
  (void)in_sizes; (void)n_in; (void)out_size; (void)ws_size;
  const float* f_q = (const float*)d_in[0];
  const float* f_k = (const float*)d_in[1];
  const float* f_v = (const float*)d_in[2];
  const int* mask  = (const int*)d_in[3];
  const float* Wq = (const float*)d_in[4];
  const float* bq = (const float*)d_in[5];
  const float* Wk = (const float*)d_in[6];
  const float* bk = (const float*)d_in[7];
  const float* Wv = (const float*)d_in[8];
  const float* bv = (const float*)d_in[9];
  const float* Wo = (const float*)d_in[10];
  const float* bo = (const float*)d_in[11];

  char* ws = (char*)d_ws;
  const size_t XB = (size_t)NTOK * DD * 2;   // 8 MB per token-matrix (bf16)
  const size_t WB = (size_t)DD * DD * 2;     // 2 MB per weight (bf16)
  u16* Xq  = (u16*)(ws);                     // reused as ctx after QKV gemm
  u16* Xk  = (u16*)(ws + XB);
  u16* Xv  = (u16*)(ws + 2 * XB);
  u16* Qp  = (u16*)(ws + 3 * XB);
  u16* Kp  = (u16*)(ws + 4 * XB);
  u16* Vt  = (u16*)(ws + 5 * XB);            // [2*1024][2048]
  u16* Wqb = (u16*)(ws + 6 * XB);
  u16* Wkb = (u16*)(ws + 6 * XB + WB);
  u16* Wvb = (u16*)(ws + 6 * XB + 2 * WB);
  u16* Wob = (u16*)(ws + 6 * XB + 3 * WB);
  float* padcnt = (float*)(ws + 6 * XB + 4 * WB);
  u16* ctx = Xq;

  PrepArgs pa;
  pa.src[0] = f_q; pa.src[1] = f_k; pa.src[2] = f_v;
  pa.src[3] = Wq;  pa.src[4] = Wk;  pa.src[5] = Wv;  pa.src[6] = Wo;
  pa.dst[0] = Xq;  pa.dst[1] = Xk;  pa.dst[2] = Xv;
  pa.dst[3] = Wqb; pa.dst[4] = Wkb; pa.dst[5] = Wvb; pa.dst[6] = Wob;
  pa.n[0] = pa.n[1] = pa.n[2] = NTOK * DD;
  pa.n[3] = pa.n[4] = pa.n[5] = pa.n[6] = DD * DD;
  pa.mask = mask; pa.padcnt = padcnt;
  prep_kernel<<<dim3(1024, 8), 256, 0, stream>>>(pa);

  QkvArgs qa;
  qa.A[0] = Xq;  qa.A[1] = Xk;  qa.A[2] = Xv;
  qa.W[0] = Wqb; qa.W[1] = Wkb; qa.W[2] = Wvb;
  qa.bias[0] = bq; qa.bias[1] = bk; qa.bias[2] = bv;
  qa.mask = mask;
  qa.outq = Qp; qa.outk = Kp; qa.outv = Vt;
  gemm_qkv_kernel<<<dim3(DD / 128, NTOK / 128, 3), 256, 0, stream>>>(qa);

  attn_kernel<<<dim3(SS / 64, HH, BB), 256, 0, stream>>>(Qp, Kp, Vt, padcnt, ctx);
  gemm_out_kernel<<<dim3(DD / 128, NTOK / 128), 256, 0, stream>>>(ctx, Wob, bo, (float*)d_out);
}